// Round 19
// baseline (194.078 us; speedup 1.0000x reference)
//
#include <hip/hip_runtime.h>
#include <hip/hip_bf16.h>

#define NROW 8192
#define NDIM 256
#define INV_T (1.0f / 0.07f)
#define K_BOT 819      // first selected descending rank
#define K_TOP 4095     // one past last selected rank
#define N_SEL 3276
#define N_UNSEL 4916   // 8192 - N_SEL (includes diagonal at -10)
#define KLO 0xC100u    // key of value 8.0
#define KHI 0xC280u    // key of value 64.0
#define RSPAN 0x180u   // 384 keys, 3 slots of 128

typedef unsigned int u32;
typedef unsigned short u16;
typedef short s16;
typedef unsigned long long u64;
typedef __bf16 bf16_t;
typedef s16 s16x8 __attribute__((ext_vector_type(8)));
typedef float f32x4 __attribute__((ext_vector_type(4)));

__device__ __forceinline__ u16 bfbits(float f) {
    return __builtin_bit_cast(u16, (bf16_t)f);   // RNE f32->bf16, raw bits
}
__device__ __forceinline__ u16 map16(u16 b) {
    return (b & 0x8000u) ? (u16)~b : (u16)(b | 0x8000u);
}
__device__ __forceinline__ float unmap16(u32 m) {
    u16 b = (m & 0x8000u) ? (u16)(m & 0x7FFFu) : (u16)~(u16)m;
    return __uint_as_float(((u32)b) << 16);
}
__device__ __forceinline__ float bf2f(s16 v) {
    return __uint_as_float(((u32)(u16)v) << 16);
}

__device__ __forceinline__ void gload16(const void* g, void* l) {
    __builtin_amdgcn_global_load_lds(
        (const __attribute__((address_space(1))) u32*)g,
        (__attribute__((address_space(3))) u32*)l, 16, 0, 0);
}

__device__ __forceinline__ u32 wave_sum_u32(u32 x) {
#pragma unroll
    for (int o = 32; o; o >>= 1) x += __shfl_down(x, o);
    return __shfl(x, 0);
}

// resolve rank `rem` within a 128-key sub-hist (packed u16 counts, 64 words)
__device__ __forceinline__ void resolve_slot(const u32* sub, int slot, u32 rem,
                                             int lane, u32* idxOut, u32* gtOut) {
    u32 word = sub[slot * 64 + lane];
    u32 c0 = word & 0xFFFFu, c1 = word >> 16;
    u32 s0 = c0 + c1, suf = s0;
#pragma unroll
    for (int o = 1; o < 64; o <<= 1) {
        u32 v = __shfl_down(suf, o);
        if (lane + o < 64) suf += v;
    }
    u32 TexL = suf - s0;
    u32 f = 0, pk = 0;
    u32 ab0 = TexL + c1;
    if (rem >= ab0 && rem < ab0 + c0) { f = 1; pk = ((u32)(lane * 2) << 16) | ab0; }
    if (rem >= TexL && rem < TexL + c1) { f = 1; pk = ((u32)(lane * 2 + 1) << 16) | TexL; }
    u64 mm = __ballot(f != 0);
    pk = __shfl(pk, (int)(__ffsll((unsigned long long)mm) - 1));
    *idxOut = pk >> 16;
    *gtOut = pk & 0xFFFFu;
}

// ---------------- fp32 -> bf16 (both inputs, one launch) ----------------
__global__ __launch_bounds__(256) void cvt_bf16(const float* __restrict__ in0,
                                                const float* __restrict__ in1,
                                                u16* __restrict__ out0,
                                                u16* __restrict__ out1) {
    int b = blockIdx.x;
    const float* in = (b < 2048) ? in0 : in1;
    u16* out = (b < 2048) ? out0 : out1;
    int i = ((b & 2047) * 256 + threadIdx.x) * 4;
    float4 v = *(const float4*)(in + i);
    ushort4 o;
    o.x = bfbits(v.x); o.y = bfbits(v.y); o.z = bfbits(v.z); o.w = bfbits(v.w);
    *(ushort4*)(out + i) = o;
}

// ---------------- fused GEMM + rank stats + LSE ----------------
// Block: 32 rows x ALL 8192 cols, K=256. A-strip LDS-resident (swizzled);
// B streamed: 64 col-tiles x 2 half-K stages, STAGE(next) || compute(cur),
// 1 barrier/step. Stats per col-tile from acc regs: cntHi in registers,
// R-range sub-hist in LDS. In-block per-row resolve (round-18 logic).
__global__ __launch_bounds__(512) void fused_rank(const u16* __restrict__ Qb,
                                                  const u16* __restrict__ Kb,
                                                  const float* __restrict__ fq,
                                                  const float* __restrict__ fk,
                                                  float* __restrict__ loss,
                                                  u32* __restrict__ flags) {
    __shared__ __align__(16) u16 sA[32 * 256];       // 16 KB
    __shared__ __align__(16) u16 sB[2][128 * 128];   // 64 KB
    __shared__ u32 hist[32 * 192];                   // 24 KB: [row][3][64]
    __shared__ u32 cntHiRow[32];

    const int tid  = threadIdx.x;
    const int lane = tid & 63;
    const int wid  = tid >> 6;      // 0..7 = col-group (16 cols)
    const int kg   = lane >> 4;
    const int fr   = lane & 15;
    const int r0   = blockIdx.x * 32;

    for (int i = tid; i < 32 * 192; i += 512) hist[i] = 0;
    if (tid < 32) cntHiRow[tid] = 0;

    // stage A-strip once: 1024 chunks, swizzled (slot jp holds chunk jp^(row&7))
#pragma unroll
    for (int s = 0; s < 2; ++s) {
        int seg = wid * 2 + s;
        int c = seg * 64 + lane;
        int row = c >> 5, jp = c & 31;
        int j = jp ^ (row & 7);
        gload16(Qb + (size_t)(r0 + row) * NDIM + j * 8, &sA[seg * 512]);
    }

    auto STAGE = [&](int buf, int step) {
        int h2 = step & 1, ct2 = step >> 1;
        u16* dst = &sB[buf][0];
#pragma unroll
        for (int s2 = 0; s2 < 4; ++s2) {
            int seg = wid * 4 + s2;
            int c = seg * 64 + lane;
            int row = c >> 4, jp = c & 15;
            int j = jp ^ (row & 7);
            gload16(Kb + (size_t)(ct2 * 128 + row) * NDIM + h2 * 128 + j * 8,
                    dst + seg * 512);
        }
    };

    STAGE(0, 0);
    __syncthreads();   // A + B(step0) ready; zeroed stats visible

    f32x4 acc[2] = {};
    u32 cntHi[2][4] = {};

    for (int s = 0; s < 128; ++s) {
        const int buf = s & 1;
        if (s + 1 < 128) STAGE(buf ^ 1, s + 1);
        const int h = s & 1, ct = s >> 1;
#pragma unroll
        for (int ks = 0; ks < 4; ++ks) {
            s16x8 bv = *(const s16x8*)&sB[buf][(wid * 16 + fr) * 128 +
                                              (((ks * 4 + kg) ^ (fr & 7)) * 8)];
#pragma unroll
            for (int m = 0; m < 2; ++m) {
                s16x8 av = *(const s16x8*)&sA[(m * 16 + fr) * 256 +
                                              (((h * 16 + ks * 4 + kg) ^ (fr & 7)) * 8)];
                acc[m] = __builtin_amdgcn_mfma_f32_16x16x32_bf16(av, bv, acc[m], 0, 0, 0);
            }
        }
        if (h == 1) {   // full K done for col-tile ct: stats + reset
            const int gcol = ct * 128 + wid * 16 + fr;
#pragma unroll
            for (int m = 0; m < 2; ++m) {
#pragma unroll
                for (int jj = 0; jj < 4; ++jj) {
                    int rowLocal = m * 16 + kg * 4 + jj;
                    u32 key = (u32)map16(bfbits(acc[m][jj]));
                    if (r0 + rowLocal != gcol) {
                        cntHi[m][jj] += (key >= KHI) ? 1u : 0u;
                        u32 d = key - KLO;
                        if (d < RSPAN)
                            atomicAdd(&hist[rowLocal * 192 + (int)(d >> 7) * 64 +
                                            (int)((key >> 1) & 63u)],
                                      (key & 1u) ? 0x10000u : 1u);
                    }
                }
                acc[m][0] = 0.f; acc[m][1] = 0.f; acc[m][2] = 0.f; acc[m][3] = 0.f;
            }
        }
        __syncthreads();   // drains staged loads; sB buf safe to overwrite
    }

    // reduce register cntHi into per-row LDS
#pragma unroll
    for (int m = 0; m < 2; ++m)
#pragma unroll
        for (int jj = 0; jj < 4; ++jj) {
            u32 v = cntHi[m][jj];
            v += __shfl_down(v, 8, 16);
            v += __shfl_down(v, 4, 16);
            v += __shfl_down(v, 2, 16);
            v += __shfl_down(v, 1, 16);
            if (fr == 0) atomicAdd(&cntHiRow[m * 16 + kg * 4 + jj], v);
        }
    __syncthreads();

    // per-row resolve: 4 rounds x 8 waves (round-18 fast path + flag)
    for (int rr = 0; rr < 4; ++rr) {
        const int rowLocal = rr * 8 + wid;
        const int grow = r0 + rowLocal;
        const u32* sub = &hist[rowLocal * 192];

        float lp;
        {
            float4 q4 = *(const float4*)(fq + (size_t)grow * NDIM + lane * 4);
            float4 k4 = *(const float4*)(fk + (size_t)grow * NDIM + lane * 4);
            float p = q4.x * k4.x + q4.y * k4.y + q4.z * k4.z + q4.w * k4.w;
#pragma unroll
            for (int o = 32; o; o >>= 1) p += __shfl_down(p, o);
            lp = __shfl(p, 0);
        }
        const u32 CH = cntHiRow[rowLocal];

        u32 T0, T1, T2;
        {
            u32 w0 = sub[lane], w1 = sub[64 + lane], w2 = sub[128 + lane];
            u32 m0 = (w0 & 0xFFFFu) + (w0 >> 16);
            u32 m1 = (w1 & 0xFFFFu) + (w1 >> 16);
            u32 m2 = (w2 & 0xFFFFu) + (w2 >> 16);
            u32 p01 = wave_sum_u32(m0 | (m1 << 16));
            T2 = wave_sum_u32(m2);
            T0 = p01 & 0xFFFFu; T1 = p01 >> 16;
        }
        const u32 NR = T0 + T1 + T2;

        bool fb = !((CH <= (u32)K_BOT) && ((u32)K_BOT < CH + NR))
                || ((u32)(K_TOP - 1) < CH + NR);

        u32 ua = 0, Ga = 0, Ea = 0;
        float a = 0.f;
        if (!fb) {
            const u32 AT2 = CH, AT1 = CH + T2, AT0 = AT1 + T1;
            int sA_;
            u32 ATA;
            if ((u32)K_BOT >= AT0)      { sA_ = 0; ATA = AT0; }
            else if ((u32)K_BOT >= AT1) { sA_ = 1; ATA = AT1; }
            else                        { sA_ = 2; ATA = AT2; }
            const u32 remA = (u32)K_BOT - ATA;
            u32 idxA, gtA;
            resolve_slot(sub, sA_, remA, lane, &idxA, &gtA);
            ua = KLO + ((u32)sA_ << 7) + idxA;
            Ga = ATA + gtA;
            {
                u32 wv = sub[sA_ * 64 + (idxA >> 1)];
                Ea = (idxA & 1u) ? (wv >> 16) : (wv & 0xFFFFu);
            }
            a = unmap16(ua);
            if (!(a >= 10.9f)) fb = true;
        }

        if (!fb) {
            const float m_ = fmaxf(fmaxf(lp, a), -10.0f) * INV_T;
            float sm = 0.f;
#pragma unroll
            for (int ss = 0; ss < 3; ++ss) {
                u32 wv = sub[ss * 64 + lane];
                u32 c0 = wv & 0xFFFFu, c1 = wv >> 16;
                u32 k0 = KLO + ((u32)ss << 7) + (u32)(lane * 2);
                u32 k1 = k0 | 1u;
                if (c0 && k0 < ua) sm += (float)c0 * __expf(unmap16(k0) * INV_T - m_);
                if (c1 && k1 < ua) sm += (float)c1 * __expf(unmap16(k1) * INV_T - m_);
            }
#pragma unroll
            for (int o = 32; o; o >>= 1) sm += __shfl_down(sm, o);
            if (lane == 0) {
                float expA = __expf(a * INV_T - m_);
                float tot = sm + (float)(int)(Ga + Ea - (u32)K_BOT) * expA;
                tot += __expf(lp * INV_T - m_)
                     + (float)N_UNSEL * __expf(-10.0f * INV_T - m_);
                loss[grow] = m_ + __logf(tot) - lp * INV_T;
                flags[grow] = 0u;
            }
        } else {
            if (lane == 0) flags[grow] = 1u;   // fixup kernel recomputes
        }
    }
}

// ---------------- fixup: exact recompute for flagged rows (rare) ----------
__global__ __launch_bounds__(256) void fixup(const u16* __restrict__ Qb,
                                             const u16* __restrict__ Kb,
                                             const float* __restrict__ fq,
                                             const float* __restrict__ fk,
                                             const u32* __restrict__ flags,
                                             float* __restrict__ loss) {
    __shared__ u16 skey[4][NROW];   // 64 KB (per-wave row buffer)
    const int wid = threadIdx.x >> 6, lane = threadIdx.x & 63;
    const int gw = blockIdx.x * 4 + wid;    // 0..255

    for (int rr = 0; rr < 32; ++rr) {
        const int row = gw * 32 + rr;
        if (!flags[row]) continue;
        u16* K = skey[wid];
        // recompute the full key row (fp32 dots from bf16 inputs)
        for (int j = 0; j < 128; ++j) {
            int c = j * 64 + lane;
            float dot = 0.f;
            for (int kc = 0; kc < 32; ++kc) {
                s16x8 qv = *(const s16x8*)(Qb + (size_t)row * NDIM + kc * 8);
                s16x8 kv = *(const s16x8*)(Kb + (size_t)c * NDIM + kc * 8);
#pragma unroll
                for (int e = 0; e < 8; ++e) dot += bf2f(qv[e]) * bf2f(kv[e]);
            }
            K[c] = (c == row) ? (u16)0 : map16(bfbits(dot));
        }
        // exact bisect for both ranks
        auto cntAbove = [&](u32 mid) {
            u32 pc = 0;
            for (int i = 0; i < 128; ++i) pc += (u32)(K[i * 64 + lane] > mid);
            return wave_sum_u32(pc);
        };
        u32 lo = 0, hi = 65535;
        while (lo < hi) { u32 mid = (lo + hi) >> 1;
            if (cntAbove(mid) <= (u32)K_BOT) hi = mid; else lo = mid + 1; }
        const u32 ua = lo;
        lo = 0; hi = 65535;
        while (lo < hi) { u32 mid = (lo + hi) >> 1;
            if (cntAbove(mid) <= (u32)(K_TOP - 1)) hi = mid; else lo = mid + 1; }
        const u32 ub = lo;
        // exact fp32 l_pos
        float lp;
        {
            float4 q4 = *(const float4*)(fq + (size_t)row * NDIM + lane * 4);
            float4 k4 = *(const float4*)(fk + (size_t)row * NDIM + lane * 4);
            float p = q4.x * k4.x + q4.y * k4.y + q4.z * k4.z + q4.w * k4.w;
#pragma unroll
            for (int o = 32; o; o >>= 1) p += __shfl_down(p, o);
            lp = __shfl(p, 0);
        }
        const float a = unmap16(ua);
        const float m_ = fmaxf(fmaxf(lp, a), -10.0f) * INV_T;
        u32 cga = 0, cea = 0, cgb = 0;
        float sm = 0.f;
        for (int i = 0; i < 128; ++i) {
            u32 u = K[i * 64 + lane];
            cga += (u > ua); cea += (u == ua); cgb += (u > ub);
            if (u > ub && u < ua) sm += __expf(unmap16(u) * INV_T - m_);
        }
        u32 Ga = wave_sum_u32(cga), Ea = wave_sum_u32(cea), Gb = wave_sum_u32(cgb);
#pragma unroll
        for (int o = 32; o; o >>= 1) sm += __shfl_down(sm, o);
        if (lane == 0) {
            float bv = unmap16(ub);
            float expA = __expf(a * INV_T - m_);
            float tot;
            if (ua == ub) {
                tot = (float)N_SEL * expA;
            } else {
                float expB = __expf(bv * INV_T - m_);
                tot = sm + (float)(int)(Ga + Ea - (u32)K_BOT) * expA
                         + (float)(int)((u32)K_TOP - Gb) * expB;
            }
            tot += __expf(lp * INV_T - m_)
                 + (float)N_UNSEL * __expf(-10.0f * INV_T - m_);
            loss[row] = m_ + __logf(tot) - lp * INV_T;
        }
    }
}

// ---------------- host ----------------
extern "C" void kernel_launch(void* const* d_in, const int* in_sizes, int n_in,
                              void* d_out, int out_size, void* d_ws, size_t ws_size,
                              hipStream_t stream) {
    const float* fq = (const float*)d_in[0];
    const float* fk = (const float*)d_in[1];
    float* out = (float*)d_out;

    char* ws = (char*)d_ws;
    u16* qb = (u16*)ws;                                   // 4 MiB
    u16* kb = qb + (size_t)NROW * NDIM;                   // 4 MiB
    u32* flags = (u32*)(ws + 2 * (size_t)NROW * NDIM * 2); // 32 KiB

    cvt_bf16<<<4096, 256, 0, stream>>>(fq, fk, qb, kb);
    fused_rank<<<256, 512, 0, stream>>>(qb, kb, fq, fk, out, flags);
    fixup<<<64, 256, 0, stream>>>(qb, kb, fq, fk, flags, out);
}